// Round 8
// baseline (90.601 us; speedup 1.0000x reference)
//
#include <hip/hip_runtime.h>

// CostVolume: out[b,c,d,h,w] = left[b,c,h,w] * right[b,c,h,w-d] (w>=d else 0),
// clipped to +-1000. B=1, C=32, H=160, W=320, D=64. Output 419.4 MB f32.
//
// R7: match the 6.9 TB/s fill kernel's structure exactly:
//  - 512 blocks (2/CU), each writing 4 consecutive (c,d) slices = 800 KB of
//    STRICTLY SEQUENTIAL output. Few write streams, forward-moving fronts.
//  - ZERO barriers / ZERO LDS -> the store queue is never drained mid-kernel
//    (R5's 40 syncthreads each forced s_waitcnt vmcnt(0) = store-pipe drain;
//    that is why sequential writes LOST in R5).
//  - All hot-loop addresses are linear inductions: left f4 = out index;
//    right A = left - ceil(d/4) f4s (slice-constant shift); B = A+1.
//    Element select within [A|B] is compile-time (template on d&3).
//  - Validity (w>=d) via w4 counter (add+wrap, no division): A zeroed when
//    qa<0, B zeroed when qa<-1; predicated loads never touch OOB addresses.
//  - Chunked bijective XCD swizzle: each XCD's 64 blocks cover 4 channels
//    (1.6 MB) -> input reads are L2-resident after first touch.
//  - nt stores (best in R2/R6 ablation), #pragma unroll 4 for load MLP.

typedef float fx4 __attribute__((ext_vector_type(4)));

constexpr float CLAMPV = 1000.0f;
constexpr int H  = 160;
constexpr int W  = 320;
constexpr int W4 = 80;                  // f4 per row
constexpr int BLOCK = 256;
constexpr int SLICE_F4 = H * W4;        // 12800 f4 per (c,d) slice
constexpr int ITERS = SLICE_F4 / BLOCK; // 50

__device__ __forceinline__ fx4 clamp4(fx4 l, fx4 r) {
    fx4 o;
    o.x = fminf(fmaxf(l.x * r.x, -CLAMPV), CLAMPV);
    o.y = fminf(fmaxf(l.y * r.y, -CLAMPV), CLAMPV);
    o.z = fminf(fmaxf(l.z * r.z, -CLAMPV), CLAMPV);
    o.w = fminf(fmaxf(l.w * r.w, -CLAMPV), CLAMPV);
    return o;
}

// Window = elements O..O+3 of [A|B], O = (4 - (d&3)) & 3.
template<int O>
__device__ __forceinline__ fx4 shuf(const fx4 A, const fx4 B) {
    if constexpr (O == 0) { return A; }
    else if constexpr (O == 1) { fx4 r = {A.y, A.z, A.w, B.x}; return r; }
    else if constexpr (O == 2) { fx4 r = {A.z, A.w, B.x, B.y}; return r; }
    else                       { fx4 r = {A.w, B.x, B.y, B.z}; return r; }
}

// One (c,d) slice, linear sweep. S = d&3.
template<int S>
__device__ __forceinline__ void slice(const fx4* __restrict__ lv,
                                      const fx4* __restrict__ rv,
                                      fx4* __restrict__ ov,
                                      const int dq, int w4) {
    constexpr int O = (4 - S) & 3;
    #pragma unroll 4
    for (int it = 0; it < ITERS; ++it) {
        const int qa = w4 - dq;             // A f4 position within the row
        fx4 A = {0.f, 0.f, 0.f, 0.f};
        fx4 B = {0.f, 0.f, 0.f, 0.f};
        if (qa >= 0)  A = rv[0];            // exec-masked: no OOB address
        if constexpr (O != 0) {
            if (qa >= -1) B = rv[1];
        }
        const fx4 r = shuf<O>(A, B);
        const fx4 l = lv[0];
        const fx4 o = clamp4(l, r);
        __builtin_nontemporal_store(o, ov);
        lv += BLOCK; rv += BLOCK; ov += BLOCK;
        w4 += 16; if (w4 >= W4) w4 -= W4;   // w4 = (t + 16*it) mod 80
    }
}

__global__ __launch_bounds__(BLOCK) void costvol_kernel(
    const float* __restrict__ left,
    const float* __restrict__ right,
    float* __restrict__ out,
    int D, int SPB)
{
    // Chunked bijective XCD swizzle: XCD x runs logical blocks
    // [x*cpx, (x+1)*cpx) -> each XCD's input working set is ~4 channels.
    int b = blockIdx.x;
    const int nwg = gridDim.x;
    if ((nwg & 7) == 0) {
        const int cpx = nwg >> 3;
        b = (b & 7) * cpx + (b >> 3);
    }

    const int t = threadIdx.x;
    const int w4_0 = t % W4;                // once per kernel

    for (int s = 0; s < SPB; ++s) {
        const int cd = b * SPB + s;
        const int c  = cd / D;              // once per slice
        const int d  = cd - c * D;
        const int dq = (d + 3) >> 2;        // ceil(d/4)

        const fx4* lv = reinterpret_cast<const fx4*>(left  + (size_t)c * H * W) + t;
        const fx4* rv = reinterpret_cast<const fx4*>(right + (size_t)c * H * W) + t - dq;
        fx4*       ov = reinterpret_cast<fx4*>(out + (size_t)cd * H * W) + t;

        switch (d & 3) {
            case 0:  slice<0>(lv, rv, ov, dq, w4_0); break;
            case 1:  slice<1>(lv, rv, ov, dq, w4_0); break;
            case 2:  slice<2>(lv, rv, ov, dq, w4_0); break;
            default: slice<3>(lv, rv, ov, dq, w4_0); break;
        }
    }
}

extern "C" void kernel_launch(void* const* d_in, const int* in_sizes, int n_in,
                              void* d_out, int out_size, void* d_ws, size_t ws_size,
                              hipStream_t stream) {
    const float* left  = (const float*)d_in[0];
    const float* right = (const float*)d_in[1];
    float* out = (float*)d_out;

    const int D = out_size / in_sizes[0];       // 64 with the fixed setup
    const int total = out_size / (H * W);       // C*D = 2048 slices

    int SPB = 4;                                // 512 blocks = 2/CU
    if (total % 4 != 0) SPB = 1;
    const int grid = total / SPB;

    costvol_kernel<<<dim3(grid), dim3(BLOCK), 0, stream>>>(left, right, out, D, SPB);
}

// Round 9
// 83.692 us; speedup vs baseline: 1.0826x; 1.0826x over previous
//
#include <hip/hip_runtime.h>

// CostVolume: out[b,c,d,h,w] = left[b,c,h,w] * right[b,c,h,w-d] (w>=d else 0),
// clipped to +-1000. B=1, C=32, H=160, W=320, D=64. Output 419.4 MB f32.
//
// R8 = R2 (best, 83.6us) with ONLY the input path changed:
//  - left: 5 f4 in REGISTERS per thread (w4 = (t+16k) mod 80 has period 5;
//    static lreg[m] indexing via 5-unrolled inner loop). No sL.
//  - right: zero-padded LDS row (16-f4 pad => w<d reads give exact 0),
//    window = 2 aligned ds_read_b128 (conflict-free 16B lane stride) +
//    9-cndmask dword select. R2's 4 guarded scalar reads were 8-way bank
//    conflicts (~80 LDS cyc/wave-iter ~= 53us/CU, same order as the store
//    floor); this cuts LDS to ~24 cyc/wave-iter.
// Store pattern / grid / block / 1 barrier / nt stores: identical to R2.

typedef float fx4 __attribute__((ext_vector_type(4)));

constexpr float CLAMPV = 1000.0f;
constexpr int C  = 32;
constexpr int H  = 160;
constexpr int W  = 320;
constexpr int W4 = 80;              // f4 per row
constexpr int BLOCK = 256;
constexpr int PADF4 = 16;           // covers d <= 64
constexpr int SRP = PADF4 + W4 + 1; // 97 f4 (1 slack on top, zeroed)

__device__ __forceinline__ fx4 clamp4(fx4 l, fx4 r) {
    fx4 o;
    o.x = fminf(fmaxf(l.x * r.x, -CLAMPV), CLAMPV);
    o.y = fminf(fmaxf(l.y * r.y, -CLAMPV), CLAMPV);
    o.z = fminf(fmaxf(l.z * r.z, -CLAMPV), CLAMPV);
    o.w = fminf(fmaxf(l.w * r.w, -CLAMPV), CLAMPV);
    return o;
}

// r[j] = Wd[o+j], Wd = {A.x,A.y,A.z,A.w,B.x,B.y,B.z}, o in 0..3 (runtime).
__device__ __forceinline__ fx4 wsel(const fx4 A, const fx4 B, const int o) {
    const bool o2 = (o & 2) != 0, o1 = (o & 1) != 0;
    const float t0 = o2 ? A.z : A.x;
    const float t1 = o2 ? A.w : A.y;
    const float t2 = o2 ? B.x : A.z;
    const float t3 = o2 ? B.y : A.w;
    const float t4 = o2 ? B.z : B.x;
    fx4 r;
    r.x = o1 ? t1 : t0;
    r.y = o1 ? t2 : t1;
    r.z = o1 ? t3 : t2;
    r.w = o1 ? t4 : t3;
    return r;
}

// Specialized D==64: 20 iterations, 4x5 with static lreg indexing.
__global__ __launch_bounds__(BLOCK) void costvol64(
    const float* __restrict__ left,
    const float* __restrict__ right,
    float* __restrict__ out)
{
    constexpr int D = 64;
    const int ch = blockIdx.x;          // c*H + h
    const int c  = ch / H;
    const int h  = ch - c * H;

    __shared__ fx4 sRp[SRP];

    const int t = threadIdx.x;
    const float* lrow = left  + (size_t)ch * W;
    const float* rrow = right + (size_t)ch * W;

    // left: 5 register f4s; w4 at iter k is (t%80 + 16*(k%5)) mod 80
    const int tw = t % W4;
    fx4 lreg[5];
    #pragma unroll
    for (int m = 0; m < 5; ++m) {
        int w4m = tw + 16 * m; if (w4m >= W4) w4m -= W4;
        lreg[m] = reinterpret_cast<const fx4*>(lrow)[w4m];
    }

    // right: padded LDS. sRp[0..15]=0 (w<d), sRp[16+q]=row f4 q, sRp[96]=0.
    if (t < W4) {
        sRp[PADF4 + t] = reinterpret_cast<const fx4*>(rrow)[t];
    } else if (t <= W4 + PADF4) {
        fx4 z = {0.f, 0.f, 0.f, 0.f};
        sRp[(t == W4 + PADF4) ? (SRP - 1) : (t - W4)] = z;
    }
    __syncthreads();

    const fx4* Ab = sRp + PADF4;        // Ab[q], q in [-16, 80]
    float* obase = out + ((size_t)c * D * H + h) * W;

    #pragma unroll 1
    for (int k5 = 0; k5 < 4; ++k5) {
        #pragma unroll
        for (int m = 0; m < 5; ++m) {
            const int k   = k5 * 5 + m;
            const int idx = t + BLOCK * k;
            const int d   = idx / W4;           // magic mul
            const int w4  = idx - d * W4;
            const int s   = 4 * w4 - d;         // window start (may be <0)
            const int qa  = s >> 2;             // floor, in [-16, 79]
            const int o   = s & 3;
            const fx4 A = Ab[qa];               // conflict-free b128
            const fx4 B = Ab[qa + 1];
            const fx4 r = wsel(A, B, o);
            const fx4 ov = clamp4(lreg[m], r);
            __builtin_nontemporal_store(ov,
                reinterpret_cast<fx4*>(obase + (size_t)d * (H * W) + 4 * w4));
        }
    }
}

// Generic fallback (any D): R2-proven guarded-scalar path. Correctness only.
__global__ __launch_bounds__(BLOCK) void costvol_generic(
    const float* __restrict__ left,
    const float* __restrict__ right,
    float* __restrict__ out,
    int D)
{
    const int ch = blockIdx.x;
    const int c  = ch / H;
    const int h  = ch - c * H;

    __shared__ float sL[W];
    __shared__ float sR[W];

    const float* lrow = left  + (size_t)ch * W;
    const float* rrow = right + (size_t)ch * W;

    const int t = threadIdx.x;
    if (t < W4) {
        reinterpret_cast<fx4*>(sL)[t] = reinterpret_cast<const fx4*>(lrow)[t];
    } else if (t < 2 * W4) {
        reinterpret_cast<fx4*>(sR)[t - W4] = reinterpret_cast<const fx4*>(rrow)[t - W4];
    }
    __syncthreads();

    float* obase = out + ((size_t)c * D * H + h) * W;
    const int total = D * W4;
    for (int idx = t; idx < total; idx += BLOCK) {
        const int d  = idx / W4;
        const int w4 = idx - d * W4;
        const int w  = w4 * 4;
        const fx4 l = reinterpret_cast<const fx4*>(sL)[w4];
        const int i0 = w - d;
        const float r0 = (i0     >= 0) ? sR[i0]     : 0.0f;
        const float r1 = (i0 + 1 >= 0) ? sR[i0 + 1] : 0.0f;
        const float r2 = (i0 + 2 >= 0) ? sR[i0 + 2] : 0.0f;
        const float r3 = (i0 + 3 >= 0) ? sR[i0 + 3] : 0.0f;
        fx4 rr = {r0, r1, r2, r3};
        const fx4 ov = clamp4(l, rr);
        __builtin_nontemporal_store(ov,
            reinterpret_cast<fx4*>(obase + (size_t)d * (H * W) + w));
    }
}

extern "C" void kernel_launch(void* const* d_in, const int* in_sizes, int n_in,
                              void* d_out, int out_size, void* d_ws, size_t ws_size,
                              hipStream_t stream) {
    const float* left  = (const float*)d_in[0];
    const float* right = (const float*)d_in[1];
    float* out = (float*)d_out;

    const int D = out_size / in_sizes[0];   // 64 with the fixed setup

    dim3 grid(C * H, 1, 1);                 // 5120 blocks, one per (c,h)
    dim3 block(BLOCK, 1, 1);
    if (D == 64) {
        costvol64<<<grid, block, 0, stream>>>(left, right, out);
    } else {
        costvol_generic<<<grid, block, 0, stream>>>(left, right, out, D);
    }
}